// Round 9
// baseline (4460.153 us; speedup 1.0000x reference)
//
#include <hip/hip_runtime.h>
#include <stdint.h>

#define NN 50000
#define NE 400000
#define EMB 384
#define NH 768
#define NL 5

typedef __bf16 bf16x8_t __attribute__((ext_vector_type(8)));
typedef float  f32x4_t  __attribute__((ext_vector_type(4)));

__device__ __forceinline__ float bflo(uint32_t u){ union{uint32_t u;float f;} v; v.u = u<<16; return v.f; }
__device__ __forceinline__ float bfhi(uint32_t u){ union{uint32_t u;float f;} v; v.u = u & 0xffff0000u; return v.f; }
__device__ __forceinline__ uint16_t f2bf(float f){
  union{float f;uint32_t u;} v; v.f=f;
  uint32_t r = v.u + 0x7fffu + ((v.u>>16)&1u);
  return (uint16_t)(r>>16);
}
__device__ __forceinline__ uint32_t bfpack2(float a, float b){
  return (uint32_t)f2bf(a) | ((uint32_t)f2bf(b)<<16);
}

// ---------------- CSR build ----------------
__global__ void hist_kernel(const int* __restrict__ dst, int* __restrict__ count){
  int i = blockIdx.x*256 + threadIdx.x;
  if (i < NE) atomicAdd(&count[dst[i]], 1);
}
__global__ void scan_block_sum(const int* __restrict__ count, int* __restrict__ bsum, int n){
  __shared__ int s[256];
  int i = blockIdx.x*256 + threadIdx.x;
  s[threadIdx.x] = (i<n) ? count[i] : 0;
  __syncthreads();
  for (int st=128; st>0; st>>=1){
    if (threadIdx.x < st) s[threadIdx.x] += s[threadIdx.x+st];
    __syncthreads();
  }
  if (threadIdx.x==0) bsum[blockIdx.x] = s[0];
}
__global__ void scan_excl_small(int* __restrict__ bsum, int nb){
  __shared__ int s[256];
  int t = threadIdx.x;
  int v = (t<nb) ? bsum[t] : 0;
  s[t] = v;
  __syncthreads();
  for (int st=1; st<256; st<<=1){
    int u = (t>=st) ? s[t-st] : 0;
    __syncthreads();
    s[t] += u;
    __syncthreads();
  }
  if (t<nb) bsum[t] = s[t] - v;
}
__global__ void scan_final(const int* __restrict__ count, const int* __restrict__ bsum,
                           int* __restrict__ rowptr, int* __restrict__ cursor, int n){
  __shared__ int s[256];
  int t = threadIdx.x;
  int i = blockIdx.x*256 + t;
  int v = (i<n) ? count[i] : 0;
  s[t] = v;
  __syncthreads();
  for (int st=1; st<256; st<<=1){
    int u = (t>=st) ? s[t-st] : 0;
    __syncthreads();
    s[t] += u;
    __syncthreads();
  }
  int off = bsum[blockIdx.x] + s[t] - v;
  if (i < n){
    rowptr[i] = off; cursor[i] = off;
    if (i == n-1) rowptr[n] = off + v;
  }
}
__global__ void scatter_kernel(const int* __restrict__ dst, const int* __restrict__ src,
                               const int* __restrict__ eattr, int* __restrict__ cursor,
                               int* __restrict__ csr_src, int* __restrict__ csr_code){
  int e = blockIdx.x*256 + threadIdx.x;
  if (e < NE){
    int p = atomicAdd(&cursor[dst[e]], 1);
    csr_src[p] = src[e];
    csr_code[p] = eattr[e*3] | (eattr[e*3+1]<<3) | (eattr[e*3+2]<<6);
  }
}

// ---------------- bond-sum table ----------------
__global__ void build_bond(const float* __restrict__ bemb, uint16_t* __restrict__ bt){
  const int code = blockIdx.x;            // 512
  const int t0 = code&7, t1=(code>>3)&7, t2=code>>6;
  const int c = threadIdx.x;              // 192 threads x 2 floats
  const float2 a = ((const float2*)(bemb + (size_t)( 0+t0)*EMB))[c];
  const float2 b = ((const float2*)(bemb + (size_t)( 8+t1)*EMB))[c];
  const float2 d = ((const float2*)(bemb + (size_t)(16+t2)*EMB))[c];
  ((uint32_t*)(bt + (size_t)code*EMB))[c] = bfpack2(a.x+b.x+d.x, a.y+b.y+d.y);
}

// ---------------- weight transpose + f32->bf16 ----------------
__global__ void transpose_w(const float* __restrict__ in, uint16_t* __restrict__ outp,
                            int R, int Cc){
  __shared__ float tile[32][33];
  const size_t lo = (size_t)blockIdx.z * R * Cc;
  int cb = blockIdx.x*32, rb = blockIdx.y*32;
  int r = rb + threadIdx.y, c = cb + threadIdx.x;
  if (r < R && c < Cc) tile[threadIdx.y][threadIdx.x] = in[lo + (size_t)r*Cc + c];
  __syncthreads();
  int orr = cb + threadIdx.y, occ = rb + threadIdx.x;
  if (orr < Cc && occ < R) outp[lo + (size_t)orr*R + occ] = f2bf(tile[threadIdx.x][threadIdx.y]);
}

// ---------------- atom encoder ----------------
__global__ __launch_bounds__(256) void atom_encode(
    const int* __restrict__ x, const float* __restrict__ aemb,
    uint16_t* __restrict__ h){
  const int w = threadIdx.x >> 6, lane = threadIdx.x & 63;
  const int i = blockIdx.x*4 + w;
  if (i >= NN) return;
  float a0=0,a1=0,a2=0,a3=0,a4=0,a5=0;
  #pragma unroll
  for (int k=0;k<9;k++){
    const int idx = x[i*9+k];
    const float2* p = (const float2*)(aemb + ((size_t)(k*64+idx))*EMB) + lane*3;
    float2 u0=p[0], u1=p[1], u2=p[2];
    a0+=u0.x; a1+=u0.y; a2+=u1.x; a3+=u1.y; a4+=u2.x; a5+=u2.y;
  }
  uint32_t* hp = (uint32_t*)(h + (size_t)i*EMB) + lane*3;
  hp[0]=bfpack2(a0,a1); hp[1]=bfpack2(a2,a3); hp[2]=bfpack2(a4,a5);
}

// ---------------- aggregation: persistent waves + atomic work queue ----------------
template<int BNREL>
__global__ __launch_bounds__(256) void agg_kernel(
    const uint16_t* __restrict__ in, const uint16_t* __restrict__ bondt,
    const float* __restrict__ scale, const float* __restrict__ shift,
    const int* __restrict__ rowptr, const int* __restrict__ csr_src,
    const int* __restrict__ csr_code, uint16_t* __restrict__ za,
    int* __restrict__ counter){
  const int lane = threadIdx.x & 63;

  float sc0=0,sc1=0,sc2=0,sc3=0,sc4=0,sc5=0, sh0=0,sh1=0,sh2=0,sh3=0,sh4=0,sh5=0;
  if (BNREL){
    const int c = lane*6;
    sc0=scale[c]; sc1=scale[c+1]; sc2=scale[c+2]; sc3=scale[c+3]; sc4=scale[c+4]; sc5=scale[c+5];
    sh0=shift[c]; sh1=shift[c+1]; sh2=shift[c+2]; sh3=shift[c+3]; sh4=shift[c+4]; sh5=shift[c+5];
  }

  for (;;){
    int i = 0;
    if (lane == 0) i = atomicAdd(counter, 1);
    i = __shfl(i, 0, 64);
    if (i >= NN) break;

    const uint32_t* hs = (const uint32_t*)(in + (size_t)i*EMB) + lane*3;
    uint32_t s0=hs[0], s1=hs[1], s2=hs[2];
    float a0,a1,a2,a3,a4,a5;
    if (BNREL){
      a0 = fmaxf(bflo(s0)*sc0+sh0, 0.f); a1 = fmaxf(bfhi(s0)*sc1+sh1, 0.f);
      a2 = fmaxf(bflo(s1)*sc2+sh2, 0.f); a3 = fmaxf(bfhi(s1)*sc3+sh3, 0.f);
      a4 = fmaxf(bflo(s2)*sc4+sh4, 0.f); a5 = fmaxf(bfhi(s2)*sc5+sh5, 0.f);
    } else {
      a0 = bflo(s0); a1 = bfhi(s0); a2 = bflo(s1); a3 = bfhi(s1); a4 = bflo(s2); a5 = bfhi(s2);
    }

    const int rs = rowptr[i], re = rowptr[i+1];
    int k = rs;
    for (; k + 4 <= re; k += 4){
      int sj[4], cj[4];
      #pragma unroll
      for (int j=0;j<4;j++){ sj[j]=csr_src[k+j]; cj[j]=csr_code[k+j]; }
      uint32_t u[4][3], b[4][3];
      #pragma unroll
      for (int j=0;j<4;j++){
        const uint32_t* hp = (const uint32_t*)(in + (size_t)sj[j]*EMB) + lane*3;
        u[j][0]=hp[0]; u[j][1]=hp[1]; u[j][2]=hp[2];
        const uint32_t* bp = (const uint32_t*)(bondt + (size_t)cj[j]*EMB) + lane*3;
        b[j][0]=bp[0]; b[j][1]=bp[1]; b[j][2]=bp[2];
      }
      #pragma unroll
      for (int j=0;j<4;j++){
        float v0,v1,v2,v3,v4,v5;
        if (BNREL){
          v0 = fmaxf(bflo(u[j][0])*sc0+sh0, 0.f); v1 = fmaxf(bfhi(u[j][0])*sc1+sh1, 0.f);
          v2 = fmaxf(bflo(u[j][1])*sc2+sh2, 0.f); v3 = fmaxf(bfhi(u[j][1])*sc3+sh3, 0.f);
          v4 = fmaxf(bflo(u[j][2])*sc4+sh4, 0.f); v5 = fmaxf(bfhi(u[j][2])*sc5+sh5, 0.f);
        } else {
          v0=bflo(u[j][0]); v1=bfhi(u[j][0]); v2=bflo(u[j][1]);
          v3=bfhi(u[j][1]); v4=bflo(u[j][2]); v5=bfhi(u[j][2]);
        }
        a0 += fmaxf(v0+bflo(b[j][0]), 0.f); a1 += fmaxf(v1+bfhi(b[j][0]), 0.f);
        a2 += fmaxf(v2+bflo(b[j][1]), 0.f); a3 += fmaxf(v3+bfhi(b[j][1]), 0.f);
        a4 += fmaxf(v4+bflo(b[j][2]), 0.f); a5 += fmaxf(v5+bfhi(b[j][2]), 0.f);
      }
    }
    for (; k < re; k++){
      const int s = csr_src[k];
      const int code = csr_code[k];
      const uint32_t* hp = (const uint32_t*)(in + (size_t)s*EMB) + lane*3;
      uint32_t u0=hp[0], u1=hp[1], u2=hp[2];
      const uint32_t* bp = (const uint32_t*)(bondt + (size_t)code*EMB) + lane*3;
      uint32_t b0=bp[0], b1=bp[1], b2=bp[2];
      float v0,v1,v2,v3,v4,v5;
      if (BNREL){
        v0 = fmaxf(bflo(u0)*sc0+sh0, 0.f); v1 = fmaxf(bfhi(u0)*sc1+sh1, 0.f);
        v2 = fmaxf(bflo(u1)*sc2+sh2, 0.f); v3 = fmaxf(bfhi(u1)*sc3+sh3, 0.f);
        v4 = fmaxf(bflo(u2)*sc4+sh4, 0.f); v5 = fmaxf(bfhi(u2)*sc5+sh5, 0.f);
      } else {
        v0=bflo(u0); v1=bfhi(u0); v2=bflo(u1); v3=bfhi(u1); v4=bflo(u2); v5=bfhi(u2);
      }
      a0 += fmaxf(v0+bflo(b0), 0.f); a1 += fmaxf(v1+bfhi(b0), 0.f);
      a2 += fmaxf(v2+bflo(b1), 0.f); a3 += fmaxf(v3+bfhi(b1), 0.f);
      a4 += fmaxf(v4+bflo(b2), 0.f); a5 += fmaxf(v5+bfhi(b2), 0.f);
    }

    uint32_t* zp = (uint32_t*)(za + (size_t)i*EMB) + lane*3;
    zp[0] = bfpack2(a0,a1);
    zp[1] = bfpack2(a2,a3);
    zp[2] = bfpack2(a4,a5);
  }
}

// ---------------- GEMM (both): 128x128 tile, scalar distance-1 register prefetch (R6) ----------------
// kq-major LDS (conflict-free), permuted B rows (dwordx2 C stores), XCD swizzle (A L2 reuse).
template<int BNA>
__global__ __launch_bounds__(256) void gemm_bt(
    const uint16_t* __restrict__ A, const uint16_t* __restrict__ Bt,
    const float* __restrict__ bias, const float* __restrict__ scA,
    const float* __restrict__ shA, uint16_t* __restrict__ C,
    float* __restrict__ stats, int M, int N, int K, int nbr){
  __shared__ __align__(16) uint16_t As[128*32];
  __shared__ __align__(16) uint16_t Bs[128*32];
  __shared__ float sAs[BNA ? NH : 1];
  __shared__ float hAs[BNA ? NH : 1];
  __shared__ float csum[128];
  __shared__ float csq[128];

  const int tid = threadIdx.x;
  const int nbc = N >> 7;
  const int xcd = blockIdx.x & 7;
  const int slot = blockIdx.x >> 3;
  const int bcol = slot % nbc;
  const int brow = (slot / nbc)*8 + xcd;
  if (brow >= nbr) return;
  const int rowbase = brow << 7;

  const int lane = tid & 63;
  const int w = tid >> 6;
  const int wm = w >> 1, wn = w & 1;
  const int quad = lane >> 4, l16 = lane & 15;

  const int s0 = tid, s1 = 256 + tid;
  const int kq0 = s0 >> 7, r0 = s0 & 127;
  const int kq1 = s1 >> 7, r1 = s1 & 127;
  int gra0 = rowbase + r0; if (gra0 >= M) gra0 = M-1;
  int gra1 = rowbase + r1; if (gra1 >= M) gra1 = M-1;
  const int pb0 = bcol*128 + (r0 & 64) + ((r0 & 15) << 2) + ((r0 >> 4) & 3);
  const int pb1 = bcol*128 + (r1 & 64) + ((r1 & 15) << 2) + ((r1 >> 4) & 3);

  const uint16_t* gA0 = A + (size_t)gra0*K + kq0*8;
  const uint16_t* gA1 = A + (size_t)gra1*K + kq1*8;
  const uint16_t* gB0 = Bt + (size_t)pb0*K + kq0*8;
  const uint16_t* gB1 = Bt + (size_t)pb1*K + kq1*8;

  // prologue: issue tile-0 loads first, then stage BN params
  uint4 ra0 = *(const uint4*)gA0;
  uint4 ra1 = *(const uint4*)gA1;
  uint4 rb0 = *(const uint4*)gB0;
  uint4 rb1 = *(const uint4*)gB1;

  if (BNA){
    for (int i = tid; i < K; i += 256){ sAs[i] = scA[i]; hAs[i] = shA[i]; }
    __syncthreads();
  }

  f32x4_t acc[4][4];
  #pragma unroll
  for (int mi=0;mi<4;mi++)
    #pragma unroll
    for (int ni=0;ni<4;ni++)
      acc[mi][ni] = (f32x4_t){0.f,0.f,0.f,0.f};

  for (int k0 = 0; k0 < K; k0 += 32){
    // write current regs -> LDS (transform if BNA)
    if (!BNA){
      *(uint4*)&As[s0*8] = ra0;
      *(uint4*)&As[s1*8] = ra1;
    } else {
      uint32_t in0[4] = {ra0.x,ra0.y,ra0.z,ra0.w};
      uint32_t in1[4] = {ra1.x,ra1.y,ra1.z,ra1.w};
      uint32_t o0[4], o1[4];
      const int kb0 = k0 + kq0*8, kb1 = k0 + kq1*8;
      #pragma unroll
      for (int j=0;j<4;j++){
        float x0 = fmaxf(bflo(in0[j])*sAs[kb0+2*j  ]+hAs[kb0+2*j  ], 0.f);
        float x1 = fmaxf(bfhi(in0[j])*sAs[kb0+2*j+1]+hAs[kb0+2*j+1], 0.f);
        o0[j] = bfpack2(x0,x1);
        float y0 = fmaxf(bflo(in1[j])*sAs[kb1+2*j  ]+hAs[kb1+2*j  ], 0.f);
        float y1 = fmaxf(bfhi(in1[j])*sAs[kb1+2*j+1]+hAs[kb1+2*j+1], 0.f);
        o1[j] = bfpack2(y0,y1);
      }
      *(uint4*)&As[s0*8] = make_uint4(o0[0],o0[1],o0[2],o0[3]);
      *(uint4*)&As[s1*8] = make_uint4(o1[0],o1[1],o1[2],o1[3]);
    }
    *(uint4*)&Bs[s0*8] = rb0;
    *(uint4*)&Bs[s1*8] = rb1;
    __syncthreads();

    // issue next-tile loads (fly during MFMA below)
    if (k0 + 32 < K){
      const int kn = k0 + 32;
      ra0 = *(const uint4*)(gA0 + kn);
      ra1 = *(const uint4*)(gA1 + kn);
      rb0 = *(const uint4*)(gB0 + kn);
      rb1 = *(const uint4*)(gB1 + kn);
    }

    bf16x8_t fa[4], fb[4];
    #pragma unroll
    for (int mi=0;mi<4;mi++)
      fa[mi] = *(const bf16x8_t*)&As[(quad*128 + wm*64 + mi*16 + l16)*8];
    #pragma unroll
    for (int ni=0;ni<4;ni++)
      fb[ni] = *(const bf16x8_t*)&Bs[(quad*128 + wn*64 + ni*16 + l16)*8];
    #pragma unroll
    for (int mi=0;mi<4;mi++)
      #pragma unroll
      for (int ni=0;ni<4;ni++)
        acc[mi][ni] = __builtin_amdgcn_mfma_f32_16x16x32_bf16(fa[mi], fb[ni], acc[mi][ni], 0,0,0);
    __syncthreads();
  }

  if (tid < 128){ csum[tid]=0.f; csq[tid]=0.f; }
  __syncthreads();

  const int lcol = wn*64 + l16*4;
  const int colbase = bcol*128 + lcol;
  float bv[4], ssum[4] = {0,0,0,0}, sq[4] = {0,0,0,0};
  #pragma unroll
  for (int ni=0;ni<4;ni++) bv[ni] = bias[colbase + ni];

  #pragma unroll
  for (int mi=0;mi<4;mi++){
    #pragma unroll
    for (int r=0;r<4;r++){
      const int grow = rowbase + wm*64 + mi*16 + quad*4 + r;
      if (grow < M){
        float v0 = acc[mi][0][r] + bv[0];
        float v1 = acc[mi][1][r] + bv[1];
        float v2 = acc[mi][2][r] + bv[2];
        float v3 = acc[mi][3][r] + bv[3];
        uint2 pk = make_uint2(bfpack2(v0,v1), bfpack2(v2,v3));
        *(uint2*)(C + (size_t)grow*N + colbase) = pk;
        ssum[0]+=v0; ssum[1]+=v1; ssum[2]+=v2; ssum[3]+=v3;
        sq[0]+=v0*v0; sq[1]+=v1*v1; sq[2]+=v2*v2; sq[3]+=v3*v3;
      }
    }
  }
  #pragma unroll
  for (int ni=0;ni<4;ni++){
    ssum[ni] += __shfl_xor(ssum[ni], 16); ssum[ni] += __shfl_xor(ssum[ni], 32);
    sq[ni]   += __shfl_xor(sq[ni],   16); sq[ni]   += __shfl_xor(sq[ni],   32);
  }
  if (quad == 0){
    #pragma unroll
    for (int ni=0;ni<4;ni++){
      atomicAdd(&csum[lcol + ni], ssum[ni]);
      atomicAdd(&csq [lcol + ni], sq[ni]);
    }
  }
  __syncthreads();
  if (tid < 128){
    atomicAdd(&stats[bcol*128 + tid], csum[tid]);
    atomicAdd(&stats[N + bcol*128 + tid], csq[tid]);
  }
}

// ---------------- BN finalize (self-clearing) ----------------
__global__ void bn_finalize(float* __restrict__ stats, const float* __restrict__ gamma,
                            const float* __restrict__ beta, float* __restrict__ scale,
                            float* __restrict__ shift, int n, float invM){
  int c = blockIdx.x*256 + threadIdx.x;
  if (c < n){
    float mean = stats[c]*invM;
    float var  = stats[n+c]*invM - mean*mean;
    float sc = gamma[c] * rsqrtf(var + 1e-5f);
    scale[c] = sc;
    shift[c] = beta[c] - mean*sc;
    stats[c] = 0.f;
    stats[n+c] = 0.f;
  }
}

// ---------------- final BN + ReLU (f32 out into d_out h region) ----------------
__global__ void bn_relu_final(const uint16_t* __restrict__ u, const float* __restrict__ scale,
                              const float* __restrict__ shift, float* __restrict__ hf){
  int i = blockIdx.x*256 + threadIdx.x;
  const int total2 = NN*EMB/2;
  if (i >= total2) return;
  uint32_t v = ((const uint32_t*)u)[i];
  int c = (i*2) % EMB;
  float f0 = fmaxf(bflo(v)*scale[c  ] + shift[c  ], 0.f);
  float f1 = fmaxf(bfhi(v)*scale[c+1] + shift[c+1], 0.f);
  ((float2*)hf)[i] = make_float2(f0, f1);
}

// ---------------- global add pool (batch sorted), h f32 in d_out ----------------
__global__ void pool_kernel(const float* __restrict__ h, const int* __restrict__ batch,
                            float* __restrict__ pool){
  __shared__ int bs[64];
  int c = threadIdx.x;
  int n0 = blockIdx.x*64;
  if (c < 64){ int i = n0 + c; bs[c] = (i < NN) ? batch[i] : -1; }
  __syncthreads();
  float sum = 0.f; int cur = -1;
  for (int tt=0; tt<64; tt++){
    int i = n0 + tt;
    if (i >= NN) break;
    int g = bs[tt];
    float v = h[(size_t)i*EMB + c];
    if (g != cur){
      if (cur >= 0) atomicAdd(&pool[(size_t)cur*EMB + c], sum);
      cur = g; sum = v;
    } else sum += v;
  }
  if (cur >= 0) atomicAdd(&pool[(size_t)cur*EMB + c], sum);
}
__global__ void pool_to_out(const float* __restrict__ pool, float* __restrict__ outp){
  int i = blockIdx.x*256 + threadIdx.x;
  if (i < 128*EMB) outp[i] = pool[i];
}

// ---------------- host orchestration ----------------
extern "C" void kernel_launch(void* const* d_in, const int* in_sizes, int n_in,
                              void* d_out, int out_size, void* d_ws, size_t ws_size,
                              hipStream_t stream){
  (void)in_sizes; (void)n_in; (void)out_size; (void)ws_size;
  const int* batch = (const int*)d_in[0];
  const int* x     = (const int*)d_in[1];
  const int* eidx  = (const int*)d_in[2];
  const int* eattr = (const int*)d_in[3];
  const float* aemb = (const float*)d_in[4];
  const float* bemb = (const float*)d_in[5];
  const float* W1 = (const float*)d_in[6];
  const float* b1 = (const float*)d_in[7];
  const float* g1 = (const float*)d_in[8];
  const float* be1= (const float*)d_in[9];
  const float* W2 = (const float*)d_in[10];
  const float* b2 = (const float*)d_in[11];
  const float* gbn= (const float*)d_in[12];
  const float* bbn= (const float*)d_in[13];
  float* out = (float*)d_out;   // [128*EMB graph_emb][NN*EMB h], both f32

  char* base = (char*)d_ws;
  size_t off = 0;
  auto alloc = [&](size_t bytes) -> void* {
    void* p = base + off;
    off = (off + bytes + 255) & ~(size_t)255;
    return p;
  };
  uint16_t* za   = (uint16_t*)alloc((size_t)NN*EMB*2);   // agg output (GEMM1 A)
  uint16_t* zm   = (uint16_t*)alloc((size_t)NN*EMB*2);   // atom-enc out / GEMM2 out
  uint16_t* t    = (uint16_t*)alloc((size_t)NN*NH*2);
  uint16_t* W1t  = (uint16_t*)alloc((size_t)NL*NH*EMB*2);
  uint16_t* W2t  = (uint16_t*)alloc((size_t)NL*EMB*NH*2);
  uint16_t* bondt= (uint16_t*)alloc((size_t)512*EMB*2);
  float* stats1  = (float*)alloc(NH*2*4);    // 6144 B, 256-aligned
  float* stats2  = (float*)alloc(EMB*2*4);   // 3072 B, contiguous after stats1
  int*   counters= (int*)alloc(256);         // NL work-queue counters, after stats2
  float* scale1  = (float*)alloc(NH*4);
  float* shift1  = (float*)alloc(NH*4);
  float* scale2  = (float*)alloc(EMB*4);
  float* shift2  = (float*)alloc(EMB*4);
  float* pool    = (float*)alloc(128*EMB*4);
  int* count   = (int*)alloc((size_t)NN*4);
  int* rowptr  = (int*)alloc((size_t)(NN+1)*4);
  int* cursor  = (int*)alloc((size_t)NN*4);
  int* bsum    = (int*)alloc(256*4);
  int* csr_src = (int*)alloc((size_t)NE*4);
  int* csr_code= (int*)alloc((size_t)NE*4);

  const int* esrc = eidx;
  const int* edst = eidx + NE;
  const int nsb = (NN + 255)/256;

  hipMemsetAsync(count, 0, (size_t)NN*4, stream);
  hist_kernel<<<(NE+255)/256, 256, 0, stream>>>(edst, count);
  scan_block_sum<<<nsb, 256, 0, stream>>>(count, bsum, NN);
  scan_excl_small<<<1, 256, 0, stream>>>(bsum, nsb);
  scan_final<<<nsb, 256, 0, stream>>>(count, bsum, rowptr, cursor, NN);
  scatter_kernel<<<(NE+255)/256, 256, 0, stream>>>(edst, esrc, eattr, cursor, csr_src, csr_code);

  build_bond<<<512, 192, 0, stream>>>(bemb, bondt);
  transpose_w<<<dim3(NH/32, EMB/32, NL), dim3(32,32), 0, stream>>>(W1, W1t, EMB, NH);
  transpose_w<<<dim3(EMB/32, NH/32, NL), dim3(32,32), 0, stream>>>(W2, W2t, NH, EMB);

  atom_encode<<<NN/4, 256, 0, stream>>>(x, aemb, zm);
  hipMemsetAsync(pool, 0, (size_t)128*EMB*4, stream);
  // stats1 (6144B) + stats2 (3072B) + counters (256B) are contiguous: one clear
  hipMemsetAsync(stats1, 0, (size_t)(6144 + 3072 + 256), stream);

  const int nbr = (NN + 127)/128;               // 391 row tiles
  const int nbrr = ((nbr + 7)/8)*8;             // 392 (XCD-swizzled)
  const int g1blocks = nbrr*(NH/128);           // 2352
  const int g2blocks = nbrr*(EMB/128);          // 1176
  const int aggblocks = 2048;                   // persistent: 8 blocks/CU x 256 CU
  for (int l = 0; l < NL; l++){
    if (l == 0)
      agg_kernel<0><<<aggblocks, 256, 0, stream>>>(zm, bondt, nullptr, nullptr,
                                                   rowptr, csr_src, csr_code, za, counters + l);
    else
      agg_kernel<1><<<aggblocks, 256, 0, stream>>>(zm, bondt, scale2, shift2,
                                                   rowptr, csr_src, csr_code, za, counters + l);
    gemm_bt<0><<<g1blocks, 256, 0, stream>>>(
        za, W1t + (size_t)l*NH*EMB, b1 + l*NH, nullptr, nullptr, t, stats1, NN, NH, EMB, nbr);
    bn_finalize<<<(NH+255)/256, 256, 0, stream>>>(stats1, g1 + l*NH, be1 + l*NH,
                                                  scale1, shift1, NH, 1.0f/NN);
    gemm_bt<1><<<g2blocks, 256, 0, stream>>>(
        t, W2t + (size_t)l*EMB*NH, b2 + l*EMB, scale1, shift1, zm, stats2, NN, EMB, NH, nbr);
    bn_finalize<<<(EMB+255)/256, 256, 0, stream>>>(stats2, gbn + l*EMB, bbn + l*EMB,
                                                   scale2, shift2, EMB, 1.0f/NN);
  }
  bn_relu_final<<<(NN*EMB/2 + 255)/256, 256, 0, stream>>>(zm, scale2, shift2, out + 128*EMB);
  pool_kernel<<<(NN+63)/64, 384, 0, stream>>>(out + 128*EMB, batch, pool);
  pool_to_out<<<(128*EMB+255)/256, 256, 0, stream>>>(pool, out);
}

// Round 10
// 1321.241 us; speedup vs baseline: 3.3757x; 3.3757x over previous
//
#include <hip/hip_runtime.h>
#include <stdint.h>

#define NN 50000
#define NE 400000
#define EMB 384
#define NH 768
#define NL 5

typedef __bf16 bf16x8_t __attribute__((ext_vector_type(8)));
typedef float  f32x4_t  __attribute__((ext_vector_type(4)));

__device__ __forceinline__ float bflo(uint32_t u){ union{uint32_t u;float f;} v; v.u = u<<16; return v.f; }
__device__ __forceinline__ float bfhi(uint32_t u){ union{uint32_t u;float f;} v; v.u = u & 0xffff0000u; return v.f; }
__device__ __forceinline__ uint16_t f2bf(float f){
  union{float f;uint32_t u;} v; v.f=f;
  uint32_t r = v.u + 0x7fffu + ((v.u>>16)&1u);
  return (uint16_t)(r>>16);
}
__device__ __forceinline__ uint32_t bfpack2(float a, float b){
  return (uint32_t)f2bf(a) | ((uint32_t)f2bf(b)<<16);
}

// ---------------- CSR build ----------------
__global__ void hist_kernel(const int* __restrict__ dst, int* __restrict__ count){
  int i = blockIdx.x*256 + threadIdx.x;
  if (i < NE) atomicAdd(&count[dst[i]], 1);
}
__global__ void scan_block_sum(const int* __restrict__ count, int* __restrict__ bsum, int n){
  __shared__ int s[256];
  int i = blockIdx.x*256 + threadIdx.x;
  s[threadIdx.x] = (i<n) ? count[i] : 0;
  __syncthreads();
  for (int st=128; st>0; st>>=1){
    if (threadIdx.x < st) s[threadIdx.x] += s[threadIdx.x+st];
    __syncthreads();
  }
  if (threadIdx.x==0) bsum[blockIdx.x] = s[0];
}
__global__ void scan_excl_small(int* __restrict__ bsum, int nb){
  __shared__ int s[256];
  int t = threadIdx.x;
  int v = (t<nb) ? bsum[t] : 0;
  s[t] = v;
  __syncthreads();
  for (int st=1; st<256; st<<=1){
    int u = (t>=st) ? s[t-st] : 0;
    __syncthreads();
    s[t] += u;
    __syncthreads();
  }
  if (t<nb) bsum[t] = s[t] - v;
}
__global__ void scan_final(const int* __restrict__ count, const int* __restrict__ bsum,
                           int* __restrict__ rowptr, int* __restrict__ cursor, int n){
  __shared__ int s[256];
  int t = threadIdx.x;
  int i = blockIdx.x*256 + t;
  int v = (i<n) ? count[i] : 0;
  s[t] = v;
  __syncthreads();
  for (int st=1; st<256; st<<=1){
    int u = (t>=st) ? s[t-st] : 0;
    __syncthreads();
    s[t] += u;
    __syncthreads();
  }
  int off = bsum[blockIdx.x] + s[t] - v;
  if (i < n){
    rowptr[i] = off; cursor[i] = off;
    if (i == n-1) rowptr[n] = off + v;
  }
}
__global__ void scatter_kernel(const int* __restrict__ dst, const int* __restrict__ src,
                               const int* __restrict__ eattr, int* __restrict__ cursor,
                               int* __restrict__ csr_src, int* __restrict__ csr_code){
  int e = blockIdx.x*256 + threadIdx.x;
  if (e < NE){
    int p = atomicAdd(&cursor[dst[e]], 1);
    csr_src[p] = src[e];
    csr_code[p] = eattr[e*3] | (eattr[e*3+1]<<3) | (eattr[e*3+2]<<6);
  }
}

// ---------------- bond-sum table ----------------
__global__ void build_bond(const float* __restrict__ bemb, uint16_t* __restrict__ bt){
  const int code = blockIdx.x;            // 512
  const int t0 = code&7, t1=(code>>3)&7, t2=code>>6;
  const int c = threadIdx.x;              // 192 threads x 2 floats
  const float2 a = ((const float2*)(bemb + (size_t)( 0+t0)*EMB))[c];
  const float2 b = ((const float2*)(bemb + (size_t)( 8+t1)*EMB))[c];
  const float2 d = ((const float2*)(bemb + (size_t)(16+t2)*EMB))[c];
  ((uint32_t*)(bt + (size_t)code*EMB))[c] = bfpack2(a.x+b.x+d.x, a.y+b.y+d.y);
}

// ---------------- weight transpose + f32->bf16 ----------------
__global__ void transpose_w(const float* __restrict__ in, uint16_t* __restrict__ outp,
                            int R, int Cc){
  __shared__ float tile[32][33];
  const size_t lo = (size_t)blockIdx.z * R * Cc;
  int cb = blockIdx.x*32, rb = blockIdx.y*32;
  int r = rb + threadIdx.y, c = cb + threadIdx.x;
  if (r < R && c < Cc) tile[threadIdx.y][threadIdx.x] = in[lo + (size_t)r*Cc + c];
  __syncthreads();
  int orr = cb + threadIdx.y, occ = rb + threadIdx.x;
  if (orr < Cc && occ < R) outp[lo + (size_t)orr*R + occ] = f2bf(tile[threadIdx.x][threadIdx.y]);
}

// ---------------- atom encoder ----------------
__global__ __launch_bounds__(256) void atom_encode(
    const int* __restrict__ x, const float* __restrict__ aemb,
    uint16_t* __restrict__ h){
  const int w = threadIdx.x >> 6, lane = threadIdx.x & 63;
  const int i = blockIdx.x*4 + w;
  if (i >= NN) return;
  float a0=0,a1=0,a2=0,a3=0,a4=0,a5=0;
  #pragma unroll
  for (int k=0;k<9;k++){
    const int idx = x[i*9+k];
    const float2* p = (const float2*)(aemb + ((size_t)(k*64+idx))*EMB) + lane*3;
    float2 u0=p[0], u1=p[1], u2=p[2];
    a0+=u0.x; a1+=u0.y; a2+=u1.x; a3+=u1.y; a4+=u2.x; a5+=u2.y;
  }
  uint32_t* hp = (uint32_t*)(h + (size_t)i*EMB) + lane*3;
  hp[0]=bfpack2(a0,a1); hp[1]=bfpack2(a2,a3); hp[2]=bfpack2(a4,a5);
}

// ---------------- aggregation (static: one wave per node — proven R6 config) ----------------
template<int BNREL>
__global__ __launch_bounds__(256) void agg_kernel(
    const uint16_t* __restrict__ in, const uint16_t* __restrict__ bondt,
    const float* __restrict__ scale, const float* __restrict__ shift,
    const int* __restrict__ rowptr, const int* __restrict__ csr_src,
    const int* __restrict__ csr_code, uint16_t* __restrict__ za){
  const int w = threadIdx.x >> 6, lane = threadIdx.x & 63;
  const int i = blockIdx.x*4 + w;
  if (i >= NN) return;

  float sc0=0,sc1=0,sc2=0,sc3=0,sc4=0,sc5=0, sh0=0,sh1=0,sh2=0,sh3=0,sh4=0,sh5=0;
  if (BNREL){
    const int c = lane*6;
    sc0=scale[c]; sc1=scale[c+1]; sc2=scale[c+2]; sc3=scale[c+3]; sc4=scale[c+4]; sc5=scale[c+5];
    sh0=shift[c]; sh1=shift[c+1]; sh2=shift[c+2]; sh3=shift[c+3]; sh4=shift[c+4]; sh5=shift[c+5];
  }

  const uint32_t* hs = (const uint32_t*)(in + (size_t)i*EMB) + lane*3;
  uint32_t s0=hs[0], s1=hs[1], s2=hs[2];
  float a0,a1,a2,a3,a4,a5;
  if (BNREL){
    a0 = fmaxf(bflo(s0)*sc0+sh0, 0.f); a1 = fmaxf(bfhi(s0)*sc1+sh1, 0.f);
    a2 = fmaxf(bflo(s1)*sc2+sh2, 0.f); a3 = fmaxf(bfhi(s1)*sc3+sh3, 0.f);
    a4 = fmaxf(bflo(s2)*sc4+sh4, 0.f); a5 = fmaxf(bfhi(s2)*sc5+sh5, 0.f);
  } else {
    a0 = bflo(s0); a1 = bfhi(s0); a2 = bflo(s1); a3 = bfhi(s1); a4 = bflo(s2); a5 = bfhi(s2);
  }

  const int rs = rowptr[i], re = rowptr[i+1];
  int k = rs;
  for (; k + 4 <= re; k += 4){
    int sj[4], cj[4];
    #pragma unroll
    for (int j=0;j<4;j++){ sj[j]=csr_src[k+j]; cj[j]=csr_code[k+j]; }
    uint32_t u[4][3], b[4][3];
    #pragma unroll
    for (int j=0;j<4;j++){
      const uint32_t* hp = (const uint32_t*)(in + (size_t)sj[j]*EMB) + lane*3;
      u[j][0]=hp[0]; u[j][1]=hp[1]; u[j][2]=hp[2];
      const uint32_t* bp = (const uint32_t*)(bondt + (size_t)cj[j]*EMB) + lane*3;
      b[j][0]=bp[0]; b[j][1]=bp[1]; b[j][2]=bp[2];
    }
    #pragma unroll
    for (int j=0;j<4;j++){
      float v0,v1,v2,v3,v4,v5;
      if (BNREL){
        v0 = fmaxf(bflo(u[j][0])*sc0+sh0, 0.f); v1 = fmaxf(bfhi(u[j][0])*sc1+sh1, 0.f);
        v2 = fmaxf(bflo(u[j][1])*sc2+sh2, 0.f); v3 = fmaxf(bfhi(u[j][1])*sc3+sh3, 0.f);
        v4 = fmaxf(bflo(u[j][2])*sc4+sh4, 0.f); v5 = fmaxf(bfhi(u[j][2])*sc5+sh5, 0.f);
      } else {
        v0=bflo(u[j][0]); v1=bfhi(u[j][0]); v2=bflo(u[j][1]);
        v3=bfhi(u[j][1]); v4=bflo(u[j][2]); v5=bfhi(u[j][2]);
      }
      a0 += fmaxf(v0+bflo(b[j][0]), 0.f); a1 += fmaxf(v1+bfhi(b[j][0]), 0.f);
      a2 += fmaxf(v2+bflo(b[j][1]), 0.f); a3 += fmaxf(v3+bfhi(b[j][1]), 0.f);
      a4 += fmaxf(v4+bflo(b[j][2]), 0.f); a5 += fmaxf(v5+bfhi(b[j][2]), 0.f);
    }
  }
  for (; k < re; k++){
    const int s = csr_src[k];
    const int code = csr_code[k];
    const uint32_t* hp = (const uint32_t*)(in + (size_t)s*EMB) + lane*3;
    uint32_t u0=hp[0], u1=hp[1], u2=hp[2];
    const uint32_t* bp = (const uint32_t*)(bondt + (size_t)code*EMB) + lane*3;
    uint32_t b0=bp[0], b1=bp[1], b2=bp[2];
    float v0,v1,v2,v3,v4,v5;
    if (BNREL){
      v0 = fmaxf(bflo(u0)*sc0+sh0, 0.f); v1 = fmaxf(bfhi(u0)*sc1+sh1, 0.f);
      v2 = fmaxf(bflo(u1)*sc2+sh2, 0.f); v3 = fmaxf(bfhi(u1)*sc3+sh3, 0.f);
      v4 = fmaxf(bflo(u2)*sc4+sh4, 0.f); v5 = fmaxf(bfhi(u2)*sc5+sh5, 0.f);
    } else {
      v0=bflo(u0); v1=bfhi(u0); v2=bflo(u1); v3=bfhi(u1); v4=bflo(u2); v5=bfhi(u2);
    }
    a0 += fmaxf(v0+bflo(b0), 0.f); a1 += fmaxf(v1+bfhi(b0), 0.f);
    a2 += fmaxf(v2+bflo(b1), 0.f); a3 += fmaxf(v3+bfhi(b1), 0.f);
    a4 += fmaxf(v4+bflo(b2), 0.f); a5 += fmaxf(v5+bfhi(b2), 0.f);
  }

  uint32_t* zp = (uint32_t*)(za + (size_t)i*EMB) + lane*3;
  zp[0] = bfpack2(a0,a1);
  zp[1] = bfpack2(a2,a3);
  zp[2] = bfpack2(a4,a5);
}

// ---------------- GEMM (both): 128x128 tile, scalar distance-1 register prefetch (R6) ----------------
// kq-major LDS (conflict-free), permuted B rows (dwordx2 C stores), XCD swizzle (A L2 reuse).
template<int BNA>
__global__ __launch_bounds__(256) void gemm_bt(
    const uint16_t* __restrict__ A, const uint16_t* __restrict__ Bt,
    const float* __restrict__ bias, const float* __restrict__ scA,
    const float* __restrict__ shA, uint16_t* __restrict__ C,
    float* __restrict__ stats, int M, int N, int K, int nbr){
  __shared__ __align__(16) uint16_t As[128*32];
  __shared__ __align__(16) uint16_t Bs[128*32];
  __shared__ float sAs[BNA ? NH : 1];
  __shared__ float hAs[BNA ? NH : 1];
  __shared__ float csum[128];
  __shared__ float csq[128];

  const int tid = threadIdx.x;
  const int nbc = N >> 7;
  const int xcd = blockIdx.x & 7;
  const int slot = blockIdx.x >> 3;
  const int bcol = slot % nbc;
  const int brow = (slot / nbc)*8 + xcd;
  if (brow >= nbr) return;
  const int rowbase = brow << 7;

  const int lane = tid & 63;
  const int w = tid >> 6;
  const int wm = w >> 1, wn = w & 1;
  const int quad = lane >> 4, l16 = lane & 15;

  const int s0 = tid, s1 = 256 + tid;
  const int kq0 = s0 >> 7, r0 = s0 & 127;
  const int kq1 = s1 >> 7, r1 = s1 & 127;
  int gra0 = rowbase + r0; if (gra0 >= M) gra0 = M-1;
  int gra1 = rowbase + r1; if (gra1 >= M) gra1 = M-1;
  const int pb0 = bcol*128 + (r0 & 64) + ((r0 & 15) << 2) + ((r0 >> 4) & 3);
  const int pb1 = bcol*128 + (r1 & 64) + ((r1 & 15) << 2) + ((r1 >> 4) & 3);

  const uint16_t* gA0 = A + (size_t)gra0*K + kq0*8;
  const uint16_t* gA1 = A + (size_t)gra1*K + kq1*8;
  const uint16_t* gB0 = Bt + (size_t)pb0*K + kq0*8;
  const uint16_t* gB1 = Bt + (size_t)pb1*K + kq1*8;

  // prologue: issue tile-0 loads first, then stage BN params
  uint4 ra0 = *(const uint4*)gA0;
  uint4 ra1 = *(const uint4*)gA1;
  uint4 rb0 = *(const uint4*)gB0;
  uint4 rb1 = *(const uint4*)gB1;

  if (BNA){
    for (int i = tid; i < K; i += 256){ sAs[i] = scA[i]; hAs[i] = shA[i]; }
    __syncthreads();
  }

  f32x4_t acc[4][4];
  #pragma unroll
  for (int mi=0;mi<4;mi++)
    #pragma unroll
    for (int ni=0;ni<4;ni++)
      acc[mi][ni] = (f32x4_t){0.f,0.f,0.f,0.f};

  for (int k0 = 0; k0 < K; k0 += 32){
    // write current regs -> LDS (transform if BNA)
    if (!BNA){
      *(uint4*)&As[s0*8] = ra0;
      *(uint4*)&As[s1*8] = ra1;
    } else {
      uint32_t in0[4] = {ra0.x,ra0.y,ra0.z,ra0.w};
      uint32_t in1[4] = {ra1.x,ra1.y,ra1.z,ra1.w};
      uint32_t o0[4], o1[4];
      const int kb0 = k0 + kq0*8, kb1 = k0 + kq1*8;
      #pragma unroll
      for (int j=0;j<4;j++){
        float x0 = fmaxf(bflo(in0[j])*sAs[kb0+2*j  ]+hAs[kb0+2*j  ], 0.f);
        float x1 = fmaxf(bfhi(in0[j])*sAs[kb0+2*j+1]+hAs[kb0+2*j+1], 0.f);
        o0[j] = bfpack2(x0,x1);
        float y0 = fmaxf(bflo(in1[j])*sAs[kb1+2*j  ]+hAs[kb1+2*j  ], 0.f);
        float y1 = fmaxf(bfhi(in1[j])*sAs[kb1+2*j+1]+hAs[kb1+2*j+1], 0.f);
        o1[j] = bfpack2(y0,y1);
      }
      *(uint4*)&As[s0*8] = make_uint4(o0[0],o0[1],o0[2],o0[3]);
      *(uint4*)&As[s1*8] = make_uint4(o1[0],o1[1],o1[2],o1[3]);
    }
    *(uint4*)&Bs[s0*8] = rb0;
    *(uint4*)&Bs[s1*8] = rb1;
    __syncthreads();

    // issue next-tile loads (fly during MFMA below)
    if (k0 + 32 < K){
      const int kn = k0 + 32;
      ra0 = *(const uint4*)(gA0 + kn);
      ra1 = *(const uint4*)(gA1 + kn);
      rb0 = *(const uint4*)(gB0 + kn);
      rb1 = *(const uint4*)(gB1 + kn);
    }

    bf16x8_t fa[4], fb[4];
    #pragma unroll
    for (int mi=0;mi<4;mi++)
      fa[mi] = *(const bf16x8_t*)&As[(quad*128 + wm*64 + mi*16 + l16)*8];
    #pragma unroll
    for (int ni=0;ni<4;ni++)
      fb[ni] = *(const bf16x8_t*)&Bs[(quad*128 + wn*64 + ni*16 + l16)*8];
    #pragma unroll
    for (int mi=0;mi<4;mi++)
      #pragma unroll
      for (int ni=0;ni<4;ni++)
        acc[mi][ni] = __builtin_amdgcn_mfma_f32_16x16x32_bf16(fa[mi], fb[ni], acc[mi][ni], 0,0,0);
    __syncthreads();
  }

  if (tid < 128){ csum[tid]=0.f; csq[tid]=0.f; }
  __syncthreads();

  const int lcol = wn*64 + l16*4;
  const int colbase = bcol*128 + lcol;
  float bv[4], ssum[4] = {0,0,0,0}, sq[4] = {0,0,0,0};
  #pragma unroll
  for (int ni=0;ni<4;ni++) bv[ni] = bias[colbase + ni];

  #pragma unroll
  for (int mi=0;mi<4;mi++){
    #pragma unroll
    for (int r=0;r<4;r++){
      const int grow = rowbase + wm*64 + mi*16 + quad*4 + r;
      if (grow < M){
        float v0 = acc[mi][0][r] + bv[0];
        float v1 = acc[mi][1][r] + bv[1];
        float v2 = acc[mi][2][r] + bv[2];
        float v3 = acc[mi][3][r] + bv[3];
        uint2 pk = make_uint2(bfpack2(v0,v1), bfpack2(v2,v3));
        *(uint2*)(C + (size_t)grow*N + colbase) = pk;
        ssum[0]+=v0; ssum[1]+=v1; ssum[2]+=v2; ssum[3]+=v3;
        sq[0]+=v0*v0; sq[1]+=v1*v1; sq[2]+=v2*v2; sq[3]+=v3*v3;
      }
    }
  }
  #pragma unroll
  for (int ni=0;ni<4;ni++){
    ssum[ni] += __shfl_xor(ssum[ni], 16); ssum[ni] += __shfl_xor(ssum[ni], 32);
    sq[ni]   += __shfl_xor(sq[ni],   16); sq[ni]   += __shfl_xor(sq[ni],   32);
  }
  if (quad == 0){
    #pragma unroll
    for (int ni=0;ni<4;ni++){
      atomicAdd(&csum[lcol + ni], ssum[ni]);
      atomicAdd(&csq [lcol + ni], sq[ni]);
    }
  }
  __syncthreads();
  if (tid < 128){
    atomicAdd(&stats[bcol*128 + tid], csum[tid]);
    atomicAdd(&stats[N + bcol*128 + tid], csq[tid]);
  }
}

// ---------------- BN finalize (self-clearing) ----------------
__global__ void bn_finalize(float* __restrict__ stats, const float* __restrict__ gamma,
                            const float* __restrict__ beta, float* __restrict__ scale,
                            float* __restrict__ shift, int n, float invM){
  int c = blockIdx.x*256 + threadIdx.x;
  if (c < n){
    float mean = stats[c]*invM;
    float var  = stats[n+c]*invM - mean*mean;
    float sc = gamma[c] * rsqrtf(var + 1e-5f);
    scale[c] = sc;
    shift[c] = beta[c] - mean*sc;
    stats[c] = 0.f;
    stats[n+c] = 0.f;
  }
}

// ---------------- final BN + ReLU (f32 out into d_out h region) ----------------
__global__ void bn_relu_final(const uint16_t* __restrict__ u, const float* __restrict__ scale,
                              const float* __restrict__ shift, float* __restrict__ hf){
  int i = blockIdx.x*256 + threadIdx.x;
  const int total2 = NN*EMB/2;
  if (i >= total2) return;
  uint32_t v = ((const uint32_t*)u)[i];
  int c = (i*2) % EMB;
  float f0 = fmaxf(bflo(v)*scale[c  ] + shift[c  ], 0.f);
  float f1 = fmaxf(bfhi(v)*scale[c+1] + shift[c+1], 0.f);
  ((float2*)hf)[i] = make_float2(f0, f1);
}

// ---------------- global add pool (batch sorted), h f32 in d_out ----------------
__global__ void pool_kernel(const float* __restrict__ h, const int* __restrict__ batch,
                            float* __restrict__ pool){
  __shared__ int bs[64];
  int c = threadIdx.x;
  int n0 = blockIdx.x*64;
  if (c < 64){ int i = n0 + c; bs[c] = (i < NN) ? batch[i] : -1; }
  __syncthreads();
  float sum = 0.f; int cur = -1;
  for (int tt=0; tt<64; tt++){
    int i = n0 + tt;
    if (i >= NN) break;
    int g = bs[tt];
    float v = h[(size_t)i*EMB + c];
    if (g != cur){
      if (cur >= 0) atomicAdd(&pool[(size_t)cur*EMB + c], sum);
      cur = g; sum = v;
    } else sum += v;
  }
  if (cur >= 0) atomicAdd(&pool[(size_t)cur*EMB + c], sum);
}
__global__ void pool_to_out(const float* __restrict__ pool, float* __restrict__ outp){
  int i = blockIdx.x*256 + threadIdx.x;
  if (i < 128*EMB) outp[i] = pool[i];
}

// ---------------- host orchestration ----------------
extern "C" void kernel_launch(void* const* d_in, const int* in_sizes, int n_in,
                              void* d_out, int out_size, void* d_ws, size_t ws_size,
                              hipStream_t stream){
  (void)in_sizes; (void)n_in; (void)out_size; (void)ws_size;
  const int* batch = (const int*)d_in[0];
  const int* x     = (const int*)d_in[1];
  const int* eidx  = (const int*)d_in[2];
  const int* eattr = (const int*)d_in[3];
  const float* aemb = (const float*)d_in[4];
  const float* bemb = (const float*)d_in[5];
  const float* W1 = (const float*)d_in[6];
  const float* b1 = (const float*)d_in[7];
  const float* g1 = (const float*)d_in[8];
  const float* be1= (const float*)d_in[9];
  const float* W2 = (const float*)d_in[10];
  const float* b2 = (const float*)d_in[11];
  const float* gbn= (const float*)d_in[12];
  const float* bbn= (const float*)d_in[13];
  float* out = (float*)d_out;   // [128*EMB graph_emb][NN*EMB h], both f32

  char* base = (char*)d_ws;
  size_t off = 0;
  auto alloc = [&](size_t bytes) -> void* {
    void* p = base + off;
    off = (off + bytes + 255) & ~(size_t)255;
    return p;
  };
  uint16_t* za   = (uint16_t*)alloc((size_t)NN*EMB*2);   // agg output (GEMM1 A)
  uint16_t* zm   = (uint16_t*)alloc((size_t)NN*EMB*2);   // atom-enc out / GEMM2 out
  uint16_t* t    = (uint16_t*)alloc((size_t)NN*NH*2);
  uint16_t* W1t  = (uint16_t*)alloc((size_t)NL*NH*EMB*2);
  uint16_t* W2t  = (uint16_t*)alloc((size_t)NL*EMB*NH*2);
  uint16_t* bondt= (uint16_t*)alloc((size_t)512*EMB*2);
  float* stats1  = (float*)alloc(NH*2*4);    // 6144 B, 256-aligned
  float* stats2  = (float*)alloc(EMB*2*4);   // 3072 B, contiguous after stats1
  float* scale1  = (float*)alloc(NH*4);
  float* shift1  = (float*)alloc(NH*4);
  float* scale2  = (float*)alloc(EMB*4);
  float* shift2  = (float*)alloc(EMB*4);
  float* pool    = (float*)alloc(128*EMB*4);
  int* count   = (int*)alloc((size_t)NN*4);
  int* rowptr  = (int*)alloc((size_t)(NN+1)*4);
  int* cursor  = (int*)alloc((size_t)NN*4);
  int* bsum    = (int*)alloc(256*4);
  int* csr_src = (int*)alloc((size_t)NE*4);
  int* csr_code= (int*)alloc((size_t)NE*4);

  const int* esrc = eidx;
  const int* edst = eidx + NE;
  const int nsb = (NN + 255)/256;

  hipMemsetAsync(count, 0, (size_t)NN*4, stream);
  hist_kernel<<<(NE+255)/256, 256, 0, stream>>>(edst, count);
  scan_block_sum<<<nsb, 256, 0, stream>>>(count, bsum, NN);
  scan_excl_small<<<1, 256, 0, stream>>>(bsum, nsb);
  scan_final<<<nsb, 256, 0, stream>>>(count, bsum, rowptr, cursor, NN);
  scatter_kernel<<<(NE+255)/256, 256, 0, stream>>>(edst, esrc, eattr, cursor, csr_src, csr_code);

  build_bond<<<512, 192, 0, stream>>>(bemb, bondt);
  transpose_w<<<dim3(NH/32, EMB/32, NL), dim3(32,32), 0, stream>>>(W1, W1t, EMB, NH);
  transpose_w<<<dim3(EMB/32, NH/32, NL), dim3(32,32), 0, stream>>>(W2, W2t, NH, EMB);

  atom_encode<<<NN/4, 256, 0, stream>>>(x, aemb, zm);
  hipMemsetAsync(pool, 0, (size_t)128*EMB*4, stream);
  // stats1 (6144B) + stats2 (3072B) contiguous: one clear; bn_finalize self-clears thereafter
  hipMemsetAsync(stats1, 0, (size_t)(6144 + 3072), stream);

  const int nbr = (NN + 127)/128;               // 391 row tiles
  const int nbrr = ((nbr + 7)/8)*8;             // 392 (XCD-swizzled)
  const int g1blocks = nbrr*(NH/128);           // 2352
  const int g2blocks = nbrr*(EMB/128);          // 1176
  for (int l = 0; l < NL; l++){
    if (l == 0)
      agg_kernel<0><<<NN/4, 256, 0, stream>>>(zm, bondt, nullptr, nullptr,
                                              rowptr, csr_src, csr_code, za);
    else
      agg_kernel<1><<<NN/4, 256, 0, stream>>>(zm, bondt, scale2, shift2,
                                              rowptr, csr_src, csr_code, za);
    gemm_bt<0><<<g1blocks, 256, 0, stream>>>(
        za, W1t + (size_t)l*NH*EMB, b1 + l*NH, nullptr, nullptr, t, stats1, NN, NH, EMB, nbr);
    bn_finalize<<<(NH+255)/256, 256, 0, stream>>>(stats1, g1 + l*NH, be1 + l*NH,
                                                  scale1, shift1, NH, 1.0f/NN);
    gemm_bt<1><<<g2blocks, 256, 0, stream>>>(
        t, W2t + (size_t)l*EMB*NH, b2 + l*EMB, scale1, shift1, zm, stats2, NN, EMB, NH, nbr);
    bn_finalize<<<(EMB+255)/256, 256, 0, stream>>>(stats2, gbn + l*EMB, bbn + l*EMB,
                                                   scale2, shift2, EMB, 1.0f/NN);
  }
  bn_relu_final<<<(NN*EMB/2 + 255)/256, 256, 0, stream>>>(zm, scale2, shift2, out + 128*EMB);
  pool_kernel<<<(NN+63)/64, 384, 0, stream>>>(out + 128*EMB, batch, pool);
  pool_to_out<<<(128*EMB+255)/256, 256, 0, stream>>>(pool, out);
}

// Round 11
// 1301.743 us; speedup vs baseline: 3.4263x; 1.0150x over previous
//
#include <hip/hip_runtime.h>
#include <stdint.h>

#define NN 50000
#define NE 400000
#define EMB 384
#define NH 768
#define NL 5

typedef __bf16 bf16x8_t __attribute__((ext_vector_type(8)));
typedef float  f32x4_t  __attribute__((ext_vector_type(4)));

__device__ __forceinline__ float bflo(uint32_t u){ union{uint32_t u;float f;} v; v.u = u<<16; return v.f; }
__device__ __forceinline__ float bfhi(uint32_t u){ union{uint32_t u;float f;} v; v.u = u & 0xffff0000u; return v.f; }
__device__ __forceinline__ uint16_t f2bf(float f){
  union{float f;uint32_t u;} v; v.f=f;
  uint32_t r = v.u + 0x7fffu + ((v.u>>16)&1u);
  return (uint16_t)(r>>16);
}
__device__ __forceinline__ uint32_t bfpack2(float a, float b){
  return (uint32_t)f2bf(a) | ((uint32_t)f2bf(b)<<16);
}

// ---------------- CSR build ----------------
__global__ void hist_kernel(const int* __restrict__ dst, int* __restrict__ count){
  int i = blockIdx.x*256 + threadIdx.x;
  if (i < NE) atomicAdd(&count[dst[i]], 1);
}
__global__ void scan_block_sum(const int* __restrict__ count, int* __restrict__ bsum, int n){
  __shared__ int s[256];
  int i = blockIdx.x*256 + threadIdx.x;
  s[threadIdx.x] = (i<n) ? count[i] : 0;
  __syncthreads();
  for (int st=128; st>0; st>>=1){
    if (threadIdx.x < st) s[threadIdx.x] += s[threadIdx.x+st];
    __syncthreads();
  }
  if (threadIdx.x==0) bsum[blockIdx.x] = s[0];
}
__global__ void scan_excl_small(int* __restrict__ bsum, int nb){
  __shared__ int s[256];
  int t = threadIdx.x;
  int v = (t<nb) ? bsum[t] : 0;
  s[t] = v;
  __syncthreads();
  for (int st=1; st<256; st<<=1){
    int u = (t>=st) ? s[t-st] : 0;
    __syncthreads();
    s[t] += u;
    __syncthreads();
  }
  if (t<nb) bsum[t] = s[t] - v;
}
__global__ void scan_final(const int* __restrict__ count, const int* __restrict__ bsum,
                           int* __restrict__ rowptr, int* __restrict__ cursor, int n){
  __shared__ int s[256];
  int t = threadIdx.x;
  int i = blockIdx.x*256 + t;
  int v = (i<n) ? count[i] : 0;
  s[t] = v;
  __syncthreads();
  for (int st=1; st<256; st<<=1){
    int u = (t>=st) ? s[t-st] : 0;
    __syncthreads();
    s[t] += u;
    __syncthreads();
  }
  int off = bsum[blockIdx.x] + s[t] - v;
  if (i < n){
    rowptr[i] = off; cursor[i] = off;
    if (i == n-1) rowptr[n] = off + v;
  }
}
__global__ void scatter_kernel(const int* __restrict__ dst, const int* __restrict__ src,
                               const int* __restrict__ eattr, int* __restrict__ cursor,
                               int* __restrict__ csr_src, int* __restrict__ csr_code){
  int e = blockIdx.x*256 + threadIdx.x;
  if (e < NE){
    int p = atomicAdd(&cursor[dst[e]], 1);
    csr_src[p] = src[e];
    csr_code[p] = eattr[e*3] | (eattr[e*3+1]<<3) | (eattr[e*3+2]<<6);
  }
}

// ---------------- bond-sum table ----------------
__global__ void build_bond(const float* __restrict__ bemb, uint16_t* __restrict__ bt){
  const int code = blockIdx.x;            // 512
  const int t0 = code&7, t1=(code>>3)&7, t2=code>>6;
  const int c = threadIdx.x;              // 192 threads x 2 floats
  const float2 a = ((const float2*)(bemb + (size_t)( 0+t0)*EMB))[c];
  const float2 b = ((const float2*)(bemb + (size_t)( 8+t1)*EMB))[c];
  const float2 d = ((const float2*)(bemb + (size_t)(16+t2)*EMB))[c];
  ((uint32_t*)(bt + (size_t)code*EMB))[c] = bfpack2(a.x+b.x+d.x, a.y+b.y+d.y);
}

// ---------------- weight transpose + f32->bf16 ----------------
__global__ void transpose_w(const float* __restrict__ in, uint16_t* __restrict__ outp,
                            int R, int Cc){
  __shared__ float tile[32][33];
  const size_t lo = (size_t)blockIdx.z * R * Cc;
  int cb = blockIdx.x*32, rb = blockIdx.y*32;
  int r = rb + threadIdx.y, c = cb + threadIdx.x;
  if (r < R && c < Cc) tile[threadIdx.y][threadIdx.x] = in[lo + (size_t)r*Cc + c];
  __syncthreads();
  int orr = cb + threadIdx.y, occ = rb + threadIdx.x;
  if (orr < Cc && occ < R) outp[lo + (size_t)orr*R + occ] = f2bf(tile[threadIdx.x][threadIdx.y]);
}

// ---------------- atom encoder ----------------
__global__ __launch_bounds__(256) void atom_encode(
    const int* __restrict__ x, const float* __restrict__ aemb,
    uint16_t* __restrict__ h){
  const int w = threadIdx.x >> 6, lane = threadIdx.x & 63;
  const int i = blockIdx.x*4 + w;
  if (i >= NN) return;
  float a0=0,a1=0,a2=0,a3=0,a4=0,a5=0;
  #pragma unroll
  for (int k=0;k<9;k++){
    const int idx = x[i*9+k];
    const float2* p = (const float2*)(aemb + ((size_t)(k*64+idx))*EMB) + lane*3;
    float2 u0=p[0], u1=p[1], u2=p[2];
    a0+=u0.x; a1+=u0.y; a2+=u1.x; a3+=u1.y; a4+=u2.x; a5+=u2.y;
  }
  uint32_t* hp = (uint32_t*)(h + (size_t)i*EMB) + lane*3;
  hp[0]=bfpack2(a0,a1); hp[1]=bfpack2(a2,a3); hp[2]=bfpack2(a4,a5);
}

// ---------------- aggregation (static: one wave per node) ----------------
template<int BNREL>
__global__ __launch_bounds__(256) void agg_kernel(
    const uint16_t* __restrict__ in, const uint16_t* __restrict__ bondt,
    const float* __restrict__ scale, const float* __restrict__ shift,
    const int* __restrict__ rowptr, const int* __restrict__ csr_src,
    const int* __restrict__ csr_code, uint16_t* __restrict__ za){
  const int w = threadIdx.x >> 6, lane = threadIdx.x & 63;
  const int i = blockIdx.x*4 + w;
  if (i >= NN) return;

  float sc0=0,sc1=0,sc2=0,sc3=0,sc4=0,sc5=0, sh0=0,sh1=0,sh2=0,sh3=0,sh4=0,sh5=0;
  if (BNREL){
    const int c = lane*6;
    sc0=scale[c]; sc1=scale[c+1]; sc2=scale[c+2]; sc3=scale[c+3]; sc4=scale[c+4]; sc5=scale[c+5];
    sh0=shift[c]; sh1=shift[c+1]; sh2=shift[c+2]; sh3=shift[c+3]; sh4=shift[c+4]; sh5=shift[c+5];
  }

  const uint32_t* hs = (const uint32_t*)(in + (size_t)i*EMB) + lane*3;
  uint32_t s0=hs[0], s1=hs[1], s2=hs[2];
  float a0,a1,a2,a3,a4,a5;
  if (BNREL){
    a0 = fmaxf(bflo(s0)*sc0+sh0, 0.f); a1 = fmaxf(bfhi(s0)*sc1+sh1, 0.f);
    a2 = fmaxf(bflo(s1)*sc2+sh2, 0.f); a3 = fmaxf(bfhi(s1)*sc3+sh3, 0.f);
    a4 = fmaxf(bflo(s2)*sc4+sh4, 0.f); a5 = fmaxf(bfhi(s2)*sc5+sh5, 0.f);
  } else {
    a0 = bflo(s0); a1 = bfhi(s0); a2 = bflo(s1); a3 = bfhi(s1); a4 = bflo(s2); a5 = bfhi(s2);
  }

  const int rs = rowptr[i], re = rowptr[i+1];
  int k = rs;
  for (; k + 4 <= re; k += 4){
    int sj[4], cj[4];
    #pragma unroll
    for (int j=0;j<4;j++){ sj[j]=csr_src[k+j]; cj[j]=csr_code[k+j]; }
    uint32_t u[4][3], b[4][3];
    #pragma unroll
    for (int j=0;j<4;j++){
      const uint32_t* hp = (const uint32_t*)(in + (size_t)sj[j]*EMB) + lane*3;
      u[j][0]=hp[0]; u[j][1]=hp[1]; u[j][2]=hp[2];
      const uint32_t* bp = (const uint32_t*)(bondt + (size_t)cj[j]*EMB) + lane*3;
      b[j][0]=bp[0]; b[j][1]=bp[1]; b[j][2]=bp[2];
    }
    #pragma unroll
    for (int j=0;j<4;j++){
      float v0,v1,v2,v3,v4,v5;
      if (BNREL){
        v0 = fmaxf(bflo(u[j][0])*sc0+sh0, 0.f); v1 = fmaxf(bfhi(u[j][0])*sc1+sh1, 0.f);
        v2 = fmaxf(bflo(u[j][1])*sc2+sh2, 0.f); v3 = fmaxf(bfhi(u[j][1])*sc3+sh3, 0.f);
        v4 = fmaxf(bflo(u[j][2])*sc4+sh4, 0.f); v5 = fmaxf(bfhi(u[j][2])*sc5+sh5, 0.f);
      } else {
        v0=bflo(u[j][0]); v1=bfhi(u[j][0]); v2=bflo(u[j][1]);
        v3=bfhi(u[j][1]); v4=bflo(u[j][2]); v5=bfhi(u[j][2]);
      }
      a0 += fmaxf(v0+bflo(b[j][0]), 0.f); a1 += fmaxf(v1+bfhi(b[j][0]), 0.f);
      a2 += fmaxf(v2+bflo(b[j][1]), 0.f); a3 += fmaxf(v3+bfhi(b[j][1]), 0.f);
      a4 += fmaxf(v4+bflo(b[j][2]), 0.f); a5 += fmaxf(v5+bfhi(b[j][2]), 0.f);
    }
  }
  for (; k < re; k++){
    const int s = csr_src[k];
    const int code = csr_code[k];
    const uint32_t* hp = (const uint32_t*)(in + (size_t)s*EMB) + lane*3;
    uint32_t u0=hp[0], u1=hp[1], u2=hp[2];
    const uint32_t* bp = (const uint32_t*)(bondt + (size_t)code*EMB) + lane*3;
    uint32_t b0=bp[0], b1=bp[1], b2=bp[2];
    float v0,v1,v2,v3,v4,v5;
    if (BNREL){
      v0 = fmaxf(bflo(u0)*sc0+sh0, 0.f); v1 = fmaxf(bfhi(u0)*sc1+sh1, 0.f);
      v2 = fmaxf(bflo(u1)*sc2+sh2, 0.f); v3 = fmaxf(bfhi(u1)*sc3+sh3, 0.f);
      v4 = fmaxf(bflo(u2)*sc4+sh4, 0.f); v5 = fmaxf(bfhi(u2)*sc5+sh5, 0.f);
    } else {
      v0=bflo(u0); v1=bfhi(u0); v2=bflo(u1); v3=bfhi(u1); v4=bflo(u2); v5=bfhi(u2);
    }
    a0 += fmaxf(v0+bflo(b0), 0.f); a1 += fmaxf(v1+bfhi(b0), 0.f);
    a2 += fmaxf(v2+bflo(b1), 0.f); a3 += fmaxf(v3+bfhi(b1), 0.f);
    a4 += fmaxf(v4+bflo(b2), 0.f); a5 += fmaxf(v5+bfhi(b2), 0.f);
  }

  uint32_t* zp = (uint32_t*)(za + (size_t)i*EMB) + lane*3;
  zp[0] = bfpack2(a0,a1);
  zp[1] = bfpack2(a2,a3);
  zp[2] = bfpack2(a4,a5);
}

// ---------------- GEMM (both): 128x128 tile, distance-2 prefetch via NAMED regs + 2x unroll ----------
// kq-major LDS (conflict-free), permuted B rows (dwordx2 C stores), XCD swizzle (A L2 reuse).
// All prefetch registers are named scalars (no arrays, no dynamic indexing -> no scratch spill).
template<int BNA>
__global__ __launch_bounds__(256) void gemm_bt(
    const uint16_t* __restrict__ A, const uint16_t* __restrict__ Bt,
    const float* __restrict__ bias, const float* __restrict__ scA,
    const float* __restrict__ shA, uint16_t* __restrict__ C,
    float* __restrict__ stats, int M, int N, int K, int nbr){
  __shared__ __align__(16) uint16_t As[128*32];
  __shared__ __align__(16) uint16_t Bs[128*32];
  __shared__ float sAs[BNA ? NH : 1];
  __shared__ float hAs[BNA ? NH : 1];
  __shared__ float csum[128];
  __shared__ float csq[128];

  const int tid = threadIdx.x;
  const int nbc = N >> 7;
  const int xcd = blockIdx.x & 7;
  const int slot = blockIdx.x >> 3;
  const int bcol = slot % nbc;
  const int brow = (slot / nbc)*8 + xcd;
  if (brow >= nbr) return;
  const int rowbase = brow << 7;

  const int lane = tid & 63;
  const int w = tid >> 6;
  const int wm = w >> 1, wn = w & 1;
  const int quad = lane >> 4, l16 = lane & 15;

  const int s0 = tid, s1 = 256 + tid;
  const int kq0 = s0 >> 7, r0 = s0 & 127;
  const int kq1 = s1 >> 7, r1 = s1 & 127;
  int gra0 = rowbase + r0; if (gra0 >= M) gra0 = M-1;
  int gra1 = rowbase + r1; if (gra1 >= M) gra1 = M-1;
  const int pb0 = bcol*128 + (r0 & 64) + ((r0 & 15) << 2) + ((r0 >> 4) & 3);
  const int pb1 = bcol*128 + (r1 & 64) + ((r1 & 15) << 2) + ((r1 >> 4) & 3);

  const uint16_t* gA0 = A + (size_t)gra0*K + kq0*8;
  const uint16_t* gA1 = A + (size_t)gra1*K + kq1*8;
  const uint16_t* gB0 = Bt + (size_t)pb0*K + kq0*8;
  const uint16_t* gB1 = Bt + (size_t)pb1*K + kq1*8;

  // prologue: tiles 0 (p*) and 1 (q*) in flight — all NAMED scalars
  uint4 pa0 = *(const uint4*)gA0;
  uint4 pa1 = *(const uint4*)gA1;
  uint4 pb0r = *(const uint4*)gB0;
  uint4 pb1r = *(const uint4*)gB1;
  uint4 qa0 = *(const uint4*)(gA0 + 32);
  uint4 qa1 = *(const uint4*)(gA1 + 32);
  uint4 qb0r = *(const uint4*)(gB0 + 32);
  uint4 qb1r = *(const uint4*)(gB1 + 32);

  if (BNA){
    for (int i = tid; i < K; i += 256){ sAs[i] = scA[i]; hAs[i] = shA[i]; }
    __syncthreads();
  }

  f32x4_t acc[4][4];
  #pragma unroll
  for (int mi=0;mi<4;mi++)
    #pragma unroll
    for (int ni=0;ni<4;ni++)
      acc[mi][ni] = (f32x4_t){0.f,0.f,0.f,0.f};

  // K is a multiple of 64 (384 or 768): pair-unrolled loop, distance-2 prefetch
  for (int k0 = 0; k0 < K; k0 += 64){
    // ---- first half: stage tile k0 (p regs) ----
    if (!BNA){
      *(uint4*)&As[s0*8] = pa0;
      *(uint4*)&As[s1*8] = pa1;
    } else {
      uint32_t in0[4] = {pa0.x,pa0.y,pa0.z,pa0.w};
      uint32_t in1[4] = {pa1.x,pa1.y,pa1.z,pa1.w};
      uint32_t o0[4], o1[4];
      const int kb0 = k0 + kq0*8, kb1 = k0 + kq1*8;
      #pragma unroll
      for (int j=0;j<4;j++){
        float x0 = fmaxf(bflo(in0[j])*sAs[kb0+2*j  ]+hAs[kb0+2*j  ], 0.f);
        float x1 = fmaxf(bfhi(in0[j])*sAs[kb0+2*j+1]+hAs[kb0+2*j+1], 0.f);
        o0[j] = bfpack2(x0,x1);
        float y0 = fmaxf(bflo(in1[j])*sAs[kb1+2*j  ]+hAs[kb1+2*j  ], 0.f);
        float y1 = fmaxf(bfhi(in1[j])*sAs[kb1+2*j+1]+hAs[kb1+2*j+1], 0.f);
        o1[j] = bfpack2(y0,y1);
      }
      *(uint4*)&As[s0*8] = make_uint4(o0[0],o0[1],o0[2],o0[3]);
      *(uint4*)&As[s1*8] = make_uint4(o1[0],o1[1],o1[2],o1[3]);
    }
    *(uint4*)&Bs[s0*8] = pb0r;
    *(uint4*)&Bs[s1*8] = pb1r;
    __syncthreads();

    // prefetch tile k0+64 into p regs (2 MFMA phases until use)
    if (k0 + 64 < K){
      const int kn = k0 + 64;
      pa0 = *(const uint4*)(gA0 + kn);
      pa1 = *(const uint4*)(gA1 + kn);
      pb0r = *(const uint4*)(gB0 + kn);
      pb1r = *(const uint4*)(gB1 + kn);
    }

    {
      bf16x8_t fa[4], fb[4];
      #pragma unroll
      for (int mi=0;mi<4;mi++)
        fa[mi] = *(const bf16x8_t*)&As[(quad*128 + wm*64 + mi*16 + l16)*8];
      #pragma unroll
      for (int ni=0;ni<4;ni++)
        fb[ni] = *(const bf16x8_t*)&Bs[(quad*128 + wn*64 + ni*16 + l16)*8];
      #pragma unroll
      for (int mi=0;mi<4;mi++)
        #pragma unroll
        for (int ni=0;ni<4;ni++)
          acc[mi][ni] = __builtin_amdgcn_mfma_f32_16x16x32_bf16(fa[mi], fb[ni], acc[mi][ni], 0,0,0);
    }
    __syncthreads();

    // ---- second half: stage tile k0+32 (q regs) ----
    if (!BNA){
      *(uint4*)&As[s0*8] = qa0;
      *(uint4*)&As[s1*8] = qa1;
    } else {
      uint32_t in0[4] = {qa0.x,qa0.y,qa0.z,qa0.w};
      uint32_t in1[4] = {qa1.x,qa1.y,qa1.z,qa1.w};
      uint32_t o0[4], o1[4];
      const int kb0 = k0 + 32 + kq0*8, kb1 = k0 + 32 + kq1*8;
      #pragma unroll
      for (int j=0;j<4;j++){
        float x0 = fmaxf(bflo(in0[j])*sAs[kb0+2*j  ]+hAs[kb0+2*j  ], 0.f);
        float x1 = fmaxf(bfhi(in0[j])*sAs[kb0+2*j+1]+hAs[kb0+2*j+1], 0.f);
        o0[j] = bfpack2(x0,x1);
        float y0 = fmaxf(bflo(in1[j])*sAs[kb1+2*j  ]+hAs[kb1+2*j  ], 0.f);
        float y1 = fmaxf(bfhi(in1[j])*sAs[kb1+2*j+1]+hAs[kb1+2*j+1], 0.f);
        o1[j] = bfpack2(y0,y1);
      }
      *(uint4*)&As[s0*8] = make_uint4(o0[0],o0[1],o0[2],o0[3]);
      *(uint4*)&As[s1*8] = make_uint4(o1[0],o1[1],o1[2],o1[3]);
    }
    *(uint4*)&Bs[s0*8] = qb0r;
    *(uint4*)&Bs[s1*8] = qb1r;
    __syncthreads();

    // prefetch tile k0+96 into q regs
    if (k0 + 96 < K){
      const int kn = k0 + 96;
      qa0 = *(const uint4*)(gA0 + kn);
      qa1 = *(const uint4*)(gA1 + kn);
      qb0r = *(const uint4*)(gB0 + kn);
      qb1r = *(const uint4*)(gB1 + kn);
    }

    {
      bf16x8_t fa[4], fb[4];
      #pragma unroll
      for (int mi=0;mi<4;mi++)
        fa[mi] = *(const bf16x8_t*)&As[(quad*128 + wm*64 + mi*16 + l16)*8];
      #pragma unroll
      for (int ni=0;ni<4;ni++)
        fb[ni] = *(const bf16x8_t*)&Bs[(quad*128 + wn*64 + ni*16 + l16)*8];
      #pragma unroll
      for (int mi=0;mi<4;mi++)
        #pragma unroll
        for (int ni=0;ni<4;ni++)
          acc[mi][ni] = __builtin_amdgcn_mfma_f32_16x16x32_bf16(fa[mi], fb[ni], acc[mi][ni], 0,0,0);
    }
    __syncthreads();
  }

  if (tid < 128){ csum[tid]=0.f; csq[tid]=0.f; }
  __syncthreads();

  const int lcol = wn*64 + l16*4;
  const int colbase = bcol*128 + lcol;
  float bv[4], ssum[4] = {0,0,0,0}, sq[4] = {0,0,0,0};
  #pragma unroll
  for (int ni=0;ni<4;ni++) bv[ni] = bias[colbase + ni];

  #pragma unroll
  for (int mi=0;mi<4;mi++){
    #pragma unroll
    for (int r=0;r<4;r++){
      const int grow = rowbase + wm*64 + mi*16 + quad*4 + r;
      if (grow < M){
        float v0 = acc[mi][0][r] + bv[0];
        float v1 = acc[mi][1][r] + bv[1];
        float v2 = acc[mi][2][r] + bv[2];
        float v3 = acc[mi][3][r] + bv[3];
        uint2 pk = make_uint2(bfpack2(v0,v1), bfpack2(v2,v3));
        *(uint2*)(C + (size_t)grow*N + colbase) = pk;
        ssum[0]+=v0; ssum[1]+=v1; ssum[2]+=v2; ssum[3]+=v3;
        sq[0]+=v0*v0; sq[1]+=v1*v1; sq[2]+=v2*v2; sq[3]+=v3*v3;
      }
    }
  }
  #pragma unroll
  for (int ni=0;ni<4;ni++){
    ssum[ni] += __shfl_xor(ssum[ni], 16); ssum[ni] += __shfl_xor(ssum[ni], 32);
    sq[ni]   += __shfl_xor(sq[ni],   16); sq[ni]   += __shfl_xor(sq[ni],   32);
  }
  if (quad == 0){
    #pragma unroll
    for (int ni=0;ni<4;ni++){
      atomicAdd(&csum[lcol + ni], ssum[ni]);
      atomicAdd(&csq [lcol + ni], sq[ni]);
    }
  }
  __syncthreads();
  if (tid < 128){
    atomicAdd(&stats[bcol*128 + tid], csum[tid]);
    atomicAdd(&stats[N + bcol*128 + tid], csq[tid]);
  }
}

// ---------------- BN finalize (self-clearing) ----------------
__global__ void bn_finalize(float* __restrict__ stats, const float* __restrict__ gamma,
                            const float* __restrict__ beta, float* __restrict__ scale,
                            float* __restrict__ shift, int n, float invM){
  int c = blockIdx.x*256 + threadIdx.x;
  if (c < n){
    float mean = stats[c]*invM;
    float var  = stats[n+c]*invM - mean*mean;
    float sc = gamma[c] * rsqrtf(var + 1e-5f);
    scale[c] = sc;
    shift[c] = beta[c] - mean*sc;
    stats[c] = 0.f;
    stats[n+c] = 0.f;
  }
}

// ---------------- final BN + ReLU (f32 out into d_out h region) ----------------
__global__ void bn_relu_final(const uint16_t* __restrict__ u, const float* __restrict__ scale,
                              const float* __restrict__ shift, float* __restrict__ hf){
  int i = blockIdx.x*256 + threadIdx.x;
  const int total2 = NN*EMB/2;
  if (i >= total2) return;
  uint32_t v = ((const uint32_t*)u)[i];
  int c = (i*2) % EMB;
  float f0 = fmaxf(bflo(v)*scale[c  ] + shift[c  ], 0.f);
  float f1 = fmaxf(bfhi(v)*scale[c+1] + shift[c+1], 0.f);
  ((float2*)hf)[i] = make_float2(f0, f1);
}

// ---------------- global add pool (batch sorted), h f32 in d_out ----------------
__global__ void pool_kernel(const float* __restrict__ h, const int* __restrict__ batch,
                            float* __restrict__ pool){
  __shared__ int bs[64];
  int c = threadIdx.x;
  int n0 = blockIdx.x*64;
  if (c < 64){ int i = n0 + c; bs[c] = (i < NN) ? batch[i] : -1; }
  __syncthreads();
  float sum = 0.f; int cur = -1;
  for (int tt=0; tt<64; tt++){
    int i = n0 + tt;
    if (i >= NN) break;
    int g = bs[tt];
    float v = h[(size_t)i*EMB + c];
    if (g != cur){
      if (cur >= 0) atomicAdd(&pool[(size_t)cur*EMB + c], sum);
      cur = g; sum = v;
    } else sum += v;
  }
  if (cur >= 0) atomicAdd(&pool[(size_t)cur*EMB + c], sum);
}
__global__ void pool_to_out(const float* __restrict__ pool, float* __restrict__ outp){
  int i = blockIdx.x*256 + threadIdx.x;
  if (i < 128*EMB) outp[i] = pool[i];
}

// ---------------- host orchestration ----------------
extern "C" void kernel_launch(void* const* d_in, const int* in_sizes, int n_in,
                              void* d_out, int out_size, void* d_ws, size_t ws_size,
                              hipStream_t stream){
  (void)in_sizes; (void)n_in; (void)out_size; (void)ws_size;
  const int* batch = (const int*)d_in[0];
  const int* x     = (const int*)d_in[1];
  const int* eidx  = (const int*)d_in[2];
  const int* eattr = (const int*)d_in[3];
  const float* aemb = (const float*)d_in[4];
  const float* bemb = (const float*)d_in[5];
  const float* W1 = (const float*)d_in[6];
  const float* b1 = (const float*)d_in[7];
  const float* g1 = (const float*)d_in[8];
  const float* be1= (const float*)d_in[9];
  const float* W2 = (const float*)d_in[10];
  const float* b2 = (const float*)d_in[11];
  const float* gbn= (const float*)d_in[12];
  const float* bbn= (const float*)d_in[13];
  float* out = (float*)d_out;   // [128*EMB graph_emb][NN*EMB h], both f32

  char* base = (char*)d_ws;
  size_t off = 0;
  auto alloc = [&](size_t bytes) -> void* {
    void* p = base + off;
    off = (off + bytes + 255) & ~(size_t)255;
    return p;
  };
  uint16_t* za   = (uint16_t*)alloc((size_t)NN*EMB*2);   // agg output (GEMM1 A)
  uint16_t* zm   = (uint16_t*)alloc((size_t)NN*EMB*2);   // atom-enc out / GEMM2 out
  uint16_t* t    = (uint16_t*)alloc((size_t)NN*NH*2);
  uint16_t* W1t  = (uint16_t*)alloc((size_t)NL*NH*EMB*2);
  uint16_t* W2t  = (uint16_t*)alloc((size_t)NL*EMB*NH*2);
  uint16_t* bondt= (uint16_t*)alloc((size_t)512*EMB*2);
  float* stats1  = (float*)alloc(NH*2*4);    // 6144 B, 256-aligned
  float* stats2  = (float*)alloc(EMB*2*4);   // 3072 B, contiguous after stats1
  float* scale1  = (float*)alloc(NH*4);
  float* shift1  = (float*)alloc(NH*4);
  float* scale2  = (float*)alloc(EMB*4);
  float* shift2  = (float*)alloc(EMB*4);
  float* pool    = (float*)alloc(128*EMB*4);
  int* count   = (int*)alloc((size_t)NN*4);
  int* rowptr  = (int*)alloc((size_t)(NN+1)*4);
  int* cursor  = (int*)alloc((size_t)NN*4);
  int* bsum    = (int*)alloc(256*4);
  int* csr_src = (int*)alloc((size_t)NE*4);
  int* csr_code= (int*)alloc((size_t)NE*4);

  const int* esrc = eidx;
  const int* edst = eidx + NE;
  const int nsb = (NN + 255)/256;

  hipMemsetAsync(count, 0, (size_t)NN*4, stream);
  hist_kernel<<<(NE+255)/256, 256, 0, stream>>>(edst, count);
  scan_block_sum<<<nsb, 256, 0, stream>>>(count, bsum, NN);
  scan_excl_small<<<1, 256, 0, stream>>>(bsum, nsb);
  scan_final<<<nsb, 256, 0, stream>>>(count, bsum, rowptr, cursor, NN);
  scatter_kernel<<<(NE+255)/256, 256, 0, stream>>>(edst, esrc, eattr, cursor, csr_src, csr_code);

  build_bond<<<512, 192, 0, stream>>>(bemb, bondt);
  transpose_w<<<dim3(NH/32, EMB/32, NL), dim3(32,32), 0, stream>>>(W1, W1t, EMB, NH);
  transpose_w<<<dim3(EMB/32, NH/32, NL), dim3(32,32), 0, stream>>>(W2, W2t, NH, EMB);

  atom_encode<<<NN/4, 256, 0, stream>>>(x, aemb, zm);
  hipMemsetAsync(pool, 0, (size_t)128*EMB*4, stream);
  // stats1 (6144B) + stats2 (3072B) contiguous: one clear; bn_finalize self-clears thereafter
  hipMemsetAsync(stats1, 0, (size_t)(6144 + 3072), stream);

  const int nbr = (NN + 127)/128;               // 391 row tiles
  const int nbrr = ((nbr + 7)/8)*8;             // 392 (XCD-swizzled)
  const int g1blocks = nbrr*(NH/128);           // 2352
  const int g2blocks = nbrr*(EMB/128);          // 1176
  for (int l = 0; l < NL; l++){
    if (l == 0)
      agg_kernel<0><<<NN/4, 256, 0, stream>>>(zm, bondt, nullptr, nullptr,
                                              rowptr, csr_src, csr_code, za);
    else
      agg_kernel<1><<<NN/4, 256, 0, stream>>>(zm, bondt, scale2, shift2,
                                              rowptr, csr_src, csr_code, za);
    gemm_bt<0><<<g1blocks, 256, 0, stream>>>(
        za, W1t + (size_t)l*NH*EMB, b1 + l*NH, nullptr, nullptr, t, stats1, NN, NH, EMB, nbr);
    bn_finalize<<<(NH+255)/256, 256, 0, stream>>>(stats1, g1 + l*NH, be1 + l*NH,
                                                  scale1, shift1, NH, 1.0f/NN);
    gemm_bt<1><<<g2blocks, 256, 0, stream>>>(
        t, W2t + (size_t)l*EMB*NH, b2 + l*EMB, scale1, shift1, zm, stats2, NN, EMB, NH, nbr);
    bn_finalize<<<(EMB+255)/256, 256, 0, stream>>>(stats2, gbn + l*EMB, bbn + l*EMB,
                                                   scale2, shift2, EMB, 1.0f/NN);
  }
  bn_relu_final<<<(NN*EMB/2 + 255)/256, 256, 0, stream>>>(zm, scale2, shift2, out + 128*EMB);
  pool_kernel<<<(NN+63)/64, 384, 0, stream>>>(out + 128*EMB, batch, pool);
  pool_to_out<<<(128*EMB+255)/256, 256, 0, stream>>>(pool, out);
}